// Round 8
// baseline (279.069 us; speedup 1.0000x reference)
//
#include <hip/hip_runtime.h>
#include <cstdint>
#include <cstddef>

#define B_   8
#define C_   1024
#define L_   1024
#define H_   16
#define CH_  64     // head dim = C/H
#define NG_  32     // groups
#define CPG_ 32     // channels per group

typedef __bf16 bf16;
typedef _Float16 f16;
typedef bf16  bf16x8 __attribute__((ext_vector_type(8)));
typedef bf16  bf16x4 __attribute__((ext_vector_type(4)));
typedef f16   f16x4  __attribute__((ext_vector_type(4)));
typedef f16   f16x2  __attribute__((ext_vector_type(2)));
typedef float f32x4  __attribute__((ext_vector_type(4)));

// log2(e)/8 : folds the attention scale (1/8) AND the exp->exp2 conversion into q
#define QSCALE 0.1803368801111203f

// ---------------------------------------------------------------------------
// async global->LDS, 16B per lane. LDS dest = wave-uniform base + lane*16.
// ---------------------------------------------------------------------------
__device__ __forceinline__ void async_cp16(void* lds, const void* g) {
  __builtin_amdgcn_global_load_lds((__attribute__((address_space(1))) void*)g,
                                   (__attribute__((address_space(3))) void*)lds,
                                   16, 0, 0);
}

// packed f32->f16 rtz convert, bit-cast to our f16x2
__device__ __forceinline__ f16x2 pk_f16(float a, float b) {
  return __builtin_bit_cast(f16x2, __builtin_amdgcn_cvt_pkrtz(a, b));
}

// LDS element offset, 32-elem (64B) rows, chunk = 8-elem (16B) unit, XOR swizzle.
// ds_read_b128 of 16 rows at fixed logical chunk -> 2-way (free, m136).
__device__ __forceinline__ int sw32(int r, int c) {
  return r * 32 + ((c ^ ((r >> 1) & 3)) << 3);
}
// LDS element offset, 64-elem (128B) rows, 8 chunks, XOR swizzle (row&7).
__device__ __forceinline__ int sw64(int r, int c) {
  return r * 64 + ((c ^ (r & 7)) << 3);
}

// ---------------------------------------------------------------------------
// fp32 -> bf16 convert (weights)
// ---------------------------------------------------------------------------
__global__ __launch_bounds__(256) void cvt_bf16_kernel(const float* __restrict__ src,
                                                       bf16* __restrict__ dst, int n4) {
  int i = blockIdx.x * 256 + threadIdx.x;
  if (i < n4) {
    float4 f = reinterpret_cast<const float4*>(src)[i];
    bf16x4 o;
    o[0] = (bf16)f.x; o[1] = (bf16)f.y; o[2] = (bf16)f.z; o[3] = (bf16)f.w;
    reinterpret_cast<bf16x4*>(dst)[i] = o;
  }
}

// ---------------------------------------------------------------------------
// GroupNorm stats: 8 blocks per (b,g), partial sums via f32 atomics.
// ---------------------------------------------------------------------------
__global__ __launch_bounds__(256) void gn_stats_kernel(const float* __restrict__ x,
                                                       float* __restrict__ stats) {
  const int bg = blockIdx.x >> 3, sl = blockIdx.x & 7;
  const int tid = threadIdx.x;
  const float* xs = x + (size_t)bg * CPG_ * L_;
  const int c = tid >> 3;
  const int lbase = sl * 128 + (tid & 7) * 4;

  float s = 0.f, s2 = 0.f;
  #pragma unroll
  for (int t = 0; t < 4; t++) {
    float4 f = *reinterpret_cast<const float4*>(xs + (size_t)c * L_ + lbase + t * 32);
    s  += f.x + f.y + f.z + f.w;
    s2 += f.x * f.x + f.y * f.y + f.z * f.z + f.w * f.w;
  }
  __shared__ float rs[256], rs2[256];
  rs[tid] = s; rs2[tid] = s2;
  __syncthreads();
  for (int d = 128; d > 0; d >>= 1) {
    if (tid < d) { rs[tid] += rs[tid + d]; rs2[tid] += rs2[tid + d]; }
    __syncthreads();
  }
  if (tid == 0) {
    atomicAdd(&stats[bg * 2],     rs[0]);
    atomicAdd(&stats[bg * 2 + 1], rs2[0]);
  }
}

// ---------------------------------------------------------------------------
// GroupNorm apply: 4 blocks per (b,g), each covers 256 l. Writes x_norm bf16
// (B,C,L) for residual and x_norm^T bf16 (B,L,C) via LDS transpose.
// ---------------------------------------------------------------------------
__global__ __launch_bounds__(256) void gn_apply_kernel(const float* __restrict__ x,
                                                       const float* __restrict__ gw,
                                                       const float* __restrict__ gb,
                                                       const float* __restrict__ stats,
                                                       bf16* __restrict__ xnb,
                                                       bf16* __restrict__ xT) {
  const int bg = blockIdx.x >> 2, l0 = (blockIdx.x & 3) * 256;
  const int b = bg >> 5, g = bg & 31;
  const int tid = threadIdx.x;
  const float* xs = x + (size_t)bg * CPG_ * L_;

  const float mean = stats[bg * 2] * (1.f / 32768.f);
  const float var  = stats[bg * 2 + 1] * (1.f / 32768.f) - mean * mean;
  const float inv  = rsqrtf(var + 1e-5f);

  __shared__ float tile[CPG_][257];
  #pragma unroll 4
  for (int c = 0; c < CPG_; c++) {
    const int gc = g * CPG_ + c;
    const float y = (xs[(size_t)c * L_ + l0 + tid] - mean) * inv * gw[gc] + gb[gc];
    xnb[(size_t)(b * C_ + gc) * L_ + l0 + tid] = (bf16)y;
    tile[c][tid] = y;
  }
  __syncthreads();
  const int c2 = tid & 31, lw = tid >> 5;
  #pragma unroll 4
  for (int jj = 0; jj < 32; jj++) {
    const int l = l0 + jj * 8 + lw;
    xT[(size_t)(b * L_ + l) * C_ + g * CPG_ + c2] = (bf16)tile[c2][jj * 8 + lw];
  }
}

// ---------------------------------------------------------------------------
// GEMM mainloop: C[m][n] = sum_k A[m][k] * Bt[n][k].
// 128x128 block tile, BK=32 DOUBLE-BUFFERED: prefetch of K-tile k+32 is issued
// right after the barrier and overlaps the whole compute phase (16 MFMA +
// 8 ds_read_b128); ONE barrier per iteration. LDS 2x(8KB A + 8KB B) = 32KB.
// global_load_lds(16B) staging, sw32 XOR-swizzled LDS.
// As/Bs must each hold 2*128*32 elements.
// ---------------------------------------------------------------------------
__device__ __forceinline__ void gemm128_bt(const bf16* __restrict__ A,
                                           const bf16* __restrict__ Bt,
                                           int lda, int ldb, int K,
                                           int m0, int n0,
                                           bf16* As, bf16* Bs,
                                           f32x4 acc[4][4]) {
  const int tid  = threadIdx.x;
  const int wave = tid >> 6, lane = tid & 63;
  const int wm = (wave >> 1) * 64, wn = (wave & 1) * 64;
  const int l4 = lane & 15, quad = lane >> 4;
  const int srow = lane >> 2;                               // staging row within 16
  const int scol = (((lane & 3) ^ ((srow >> 1) & 3)) << 3); // swizzled src chunk

  const bf16* ga = A  + (size_t)(m0 + wave * 16 + srow) * lda + scol;
  const bf16* gb = Bt + (size_t)(n0 + wave * 16 + srow) * ldb + scol;
  const int woff = wave * 512;          // wave*16 rows * 32 elems

  // prologue: stage k0=0 into buffer 0
  async_cp16(As + woff,        ga);
  async_cp16(As + 2048 + woff, ga + (size_t)64 * lda);
  async_cp16(Bs + woff,        gb);
  async_cp16(Bs + 2048 + woff, gb + (size_t)64 * ldb);
  __syncthreads();

  for (int k0 = 0; k0 < K; k0 += 32) {
    const int cur = (k0 >> 5) & 1;
    // prefetch next K-tile into the other buffer; overlaps compute below
    if (k0 + 32 < K) {
      const int nxt = (cur ^ 1) * 4096;
      async_cp16(As + nxt + woff,        ga + k0 + 32);
      async_cp16(As + nxt + 2048 + woff, ga + (size_t)64 * lda + k0 + 32);
      async_cp16(Bs + nxt + woff,        gb + k0 + 32);
      async_cp16(Bs + nxt + 2048 + woff, gb + (size_t)64 * ldb + k0 + 32);
    }
    const bf16* Ac = As + cur * 4096;
    const bf16* Bc = Bs + cur * 4096;

    bf16x8 af[4], bfv[4];
    #pragma unroll
    for (int i = 0; i < 4; i++) {
      af[i] = *reinterpret_cast<const bf16x8*>(Ac + sw32(wm + i * 16 + l4, quad));
    }
    #pragma unroll
    for (int j = 0; j < 4; j++) {
      bfv[j] = *reinterpret_cast<const bf16x8*>(Bc + sw32(wn + j * 16 + l4, quad));
    }
    #pragma unroll
    for (int i = 0; i < 4; i++) {
      #pragma unroll
      for (int j = 0; j < 4; j++) {
        acc[i][j] = __builtin_amdgcn_mfma_f32_16x16x32_bf16(af[i], bfv[j], acc[i][j], 0, 0, 0);
      }
    }
    __syncthreads();   // drains prefetch (had full compute phase to land)
  }
}

// ---------------------------------------------------------------------------
// QKV GEMM: A = qkv_w bf16 (3072x1024), Bt = x_norm^T (per batch, 1024x1024).
// Epilogue: +bias; q scaled by log2(e)/8 -> (b,h,L,64); k -> (b,h,L,64);
// v -> fp16 (b,h,64,L) with an 8B-slot swizzle inside each 128B segment:
//   slot8' = slot8 ^ (c & 15)   (c = head channel)
// so that attention's LDS image gives conflict-free PV ds_read_b64.
// ---------------------------------------------------------------------------
__global__ __launch_bounds__(256, 4) void qkv_gemm_kernel(const bf16* __restrict__ Wq,
                                                          const bf16* __restrict__ xT,
                                                          const float* __restrict__ bias,
                                                          bf16* __restrict__ qT,
                                                          bf16* __restrict__ kT,
                                                          f16* __restrict__ vB) {
  __shared__ bf16 As[2 * 128 * 32], Bs[2 * 128 * 32];
  const int bi = blockIdx.z;
  const int m0 = blockIdx.y * 128, n0 = blockIdx.x * 128;

  f32x4 acc[4][4];
  #pragma unroll
  for (int i = 0; i < 4; i++) {
    #pragma unroll
    for (int j = 0; j < 4; j++) { acc[i][j] = (f32x4){0.f, 0.f, 0.f, 0.f}; }
  }

  gemm128_bt(Wq, xT + (size_t)bi * L_ * C_, C_, C_, C_, m0, n0, As, Bs, acc);

  const int tid = threadIdx.x;
  const int wave = tid >> 6, lane = tid & 63;
  const int wm = (wave >> 1) * 64, wn = (wave & 1) * 64;
  const int l4 = lane & 15, quad = lane >> 4;

  #pragma unroll
  for (int i = 0; i < 4; i++) {
    const int ob = m0 + wm + i * 16 + quad * 4;   // rows ob..ob+3 (same head/section)
    const int h = ob / 192, r = ob % 192;
    const int sec = r >> 6, c = r & 63;
    float bb[4];
    #pragma unroll
    for (int rg = 0; rg < 4; rg++) { bb[rg] = bias[ob + rg]; }
    #pragma unroll
    for (int j = 0; j < 4; j++) {
      const int l = n0 + wn + j * 16 + l4;
      f32x4 a = acc[i][j];
      if (sec == 2) {
        const int e = l & 63, g64 = l >> 6;
        #pragma unroll
        for (int rg = 0; rg < 4; rg++) {
          const int cc = c + rg;
          const int ep = ((((e >> 2) ^ cc) & 15) << 2) | (e & 3);
          vB[(size_t)((bi * H_ + h) * CH_ + cc) * L_ + (g64 << 6) + ep] =
              (f16)(a[rg] + bb[rg]);
        }
      } else {
        const float sc = (sec == 0) ? QSCALE : 1.0f;
        bf16* dst = (sec == 0 ? qT : kT) + (size_t)((bi * H_ + h) * L_ + l) * CH_ + c;
        bf16x4 o;
        #pragma unroll
        for (int rg = 0; rg < 4; rg++) { o[rg] = (bf16)((a[rg] + bb[rg]) * sc); }
        *reinterpret_cast<bf16x4*>(dst) = o;
      }
    }
  }
}

// ---------------------------------------------------------------------------
// Flash attention, S^T formulation, 128 t-rows/block, grid 1024 (4 blocks/CU).
// LDS overlay (32KB total): Q tile (16KB) is consumed into registers right
// after staging, then its region is reused as K/V double-buffer slot 1.
// Double-buffered K/V prefetch overlaps compute; ONE barrier per s-iter.
// l (sum of exp) accumulated via MFMA with a ones-B operand.
// qT/kT: (head, L, 64) bf16 (q pre-scaled by log2(e)/8);
// vB: (head, 64, L) f16, 8B-slot-swizzled -> conflict-free PV ds_read_b64.
// out aT: (B, L, C) bf16.
// ---------------------------------------------------------------------------
__global__ __launch_bounds__(256, 4) void attn_kernel(const bf16* __restrict__ qT,
                                                      const bf16* __restrict__ kT,
                                                      const f16* __restrict__ vB,
                                                      bf16* __restrict__ aT) {
  const int tid = threadIdx.x, wave = tid >> 6, lane = tid & 63;
  const int l4 = lane & 15, quad = lane >> 4;
  const int rsub = lane >> 3;
  const int csrc = ((lane & 7) ^ rsub) << 3;   // swizzled source chunk (q/k only)

  // layout: buf0 K at 0, buf0 V at 8K; buf1 K at 16K, buf1 V at 24K.
  // Q initially staged at 16K (buf1 region), consumed to regs before buf1 use.
  __shared__ char smem[32768];

  const int tile = blockIdx.x;               // 0..1023
  const int t0 = (tile & 7) * 128;
  const int hb = tile >> 3;                  // b*16 + h
  const bf16* q = qT + (size_t)hb * L_ * CH_;
  const bf16* k = kT + (size_t)hb * L_ * CH_;
  const f16*  v = vB + (size_t)hb * CH_ * L_;

  // stage Q tile (16KB, at smem+16K) + first K/V tiles into buf 0
  {
    const bf16* gq = q + (size_t)t0 * CH_;
    #pragma unroll
    for (int i = wave; i < 16; i += 4) {
      async_cp16(smem + 16384 + i * 1024, gq + (i * 8 + rsub) * 64 + csrc);
    }
    #pragma unroll
    for (int i = wave; i < 8; i += 4) {
      async_cp16(smem + i * 1024, k + (size_t)(i * 8 + rsub) * 64 + csrc);
      async_cp16(smem + 8192 + i * 1024, v + (size_t)(i * 8 + rsub) * L_ + ((lane & 7) << 3));
    }
  }
  __syncthreads();

  // Q as B-operand: B[k=c=quad*8+jj][n=t=l4]; two 16-col groups per wave (u)
  bf16x8 bq0[2], bq1[2];
  {
    const bf16* qs = (const bf16*)(smem + 16384);
    #pragma unroll
    for (int u = 0; u < 2; u++) {
      bq0[u] = *reinterpret_cast<const bf16x8*>(qs + sw64(wave * 32 + u * 16 + l4, quad));
      bq1[u] = *reinterpret_cast<const bf16x8*>(qs + sw64(wave * 32 + u * 16 + l4, quad + 4));
    }
  }
  __syncthreads();   // all waves have Q in regs; qs region is now free (buf1)

  f32x4 oacc[2][4];              // [u][ct], rows t=quad*4+r, cols c=ct*16+l4
  f32x4 lacc[2];                 // running sum(exp), same row layout as oacc
  float m_s[2];                  // running max for t = u*16 + l4
  #pragma unroll
  for (int u = 0; u < 2; u++) {
    #pragma unroll
    for (int ct = 0; ct < 4; ct++) { oacc[u][ct] = (f32x4){0.f, 0.f, 0.f, 0.f}; }
    lacc[u] = (f32x4){0.f, 0.f, 0.f, 0.f};
    m_s[u] = -1e30f;
  }

  const f16x4 vone = {(f16)1.f, (f16)1.f, (f16)1.f, (f16)1.f};

  for (int it = 0; it < 16; it++) {
    const int cur = it & 1;
    // prefetch next K/V tile into the other buffer; overlaps compute below
    if (it < 15) {
      const int s1 = (it + 1) * 64;
      char* nb = smem + (cur ^ 1) * 16384;
      const bf16* gk = k + (size_t)s1 * CH_;
      const f16*  gv = v + s1;
      #pragma unroll
      for (int i = wave; i < 8; i += 4) {
        async_cp16(nb + i * 1024, gk + (size_t)(i * 8 + rsub) * 64 + csrc);
        async_cp16(nb + 8192 + i * 1024, gv + (size_t)(i * 8 + rsub) * L_ + ((lane & 7) << 3));
      }
    }
    const bf16* ksc = (const bf16*)(smem + cur * 16384);
    const f16*  vsc = (const f16*)(smem + cur * 16384 + 8192);

    // S^T tiles: lane holds S[s=16j+quad*4+r][t = u*16 + l4] in st[u][j][r]
    f32x4 st[2][4];
    #pragma unroll
    for (int j = 0; j < 4; j++) {
      const bf16x8 ak0 = *reinterpret_cast<const bf16x8*>(ksc + sw64(j * 16 + l4, quad));
      const bf16x8 ak1 = *reinterpret_cast<const bf16x8*>(ksc + sw64(j * 16 + l4, quad + 4));
      #pragma unroll
      for (int u = 0; u < 2; u++) {
        f32x4 z = (f32x4){0.f, 0.f, 0.f, 0.f};
        z = __builtin_amdgcn_mfma_f32_16x16x32_bf16(ak0, bq0[u], z, 0, 0, 0);
        z = __builtin_amdgcn_mfma_f32_16x16x32_bf16(ak1, bq1[u], z, 0, 0, 0);
        st[u][j] = z;
      }
    }

    // running-max update (base-2 domain; q pre-scaled by log2(e)/8)
    float alpha[2], mn[2];
    #pragma unroll
    for (int u = 0; u < 2; u++) {
      float mx = fmaxf(fmaxf(st[u][0][0], st[u][0][1]), fmaxf(st[u][0][2], st[u][0][3]));
      #pragma unroll
      for (int j = 1; j < 4; j++) {
        mx = fmaxf(mx, fmaxf(fmaxf(st[u][j][0], st[u][j][1]), fmaxf(st[u][j][2], st[u][j][3])));
      }
      mx = fmaxf(mx, __shfl_xor(mx, 16));
      mx = fmaxf(mx, __shfl_xor(mx, 32));
      mn[u] = fmaxf(m_s[u], mx);
      alpha[u] = __builtin_amdgcn_exp2f(m_s[u] - mn[u]);
      m_s[u] = mn[u];
    }

    // rescale history only when some row's max moved (alpha != 1 exactly)
    if (__any(alpha[0] != 1.0f || alpha[1] != 1.0f)) {
      #pragma unroll
      for (int u = 0; u < 2; u++) {
        float ar[4];
        #pragma unroll
        for (int r = 0; r < 4; r++) { ar[r] = __shfl(alpha[u], quad * 4 + r); }
        #pragma unroll
        for (int ct = 0; ct < 4; ct++) {
          #pragma unroll
          for (int r = 0; r < 4; r++) { oacc[u][ct][r] *= ar[r]; }
        }
        #pragma unroll
        for (int r = 0; r < 4; r++) { lacc[u][r] *= ar[r]; }
      }
    }

    // P = exp2(S - m) as f16 A-fragments; l accumulated via MFMA with ones-B
    f16x4 pa[2][4];
    #pragma unroll
    for (int u = 0; u < 2; u++) {
      #pragma unroll
      for (int j = 0; j < 4; j++) {
        const float p0 = __builtin_amdgcn_exp2f(st[u][j][0] - mn[u]);
        const float p1 = __builtin_amdgcn_exp2f(st[u][j][1] - mn[u]);
        const float p2 = __builtin_amdgcn_exp2f(st[u][j][2] - mn[u]);
        const float p3 = __builtin_amdgcn_exp2f(st[u][j][3] - mn[u]);
        pa[u][j] = __builtin_shufflevector(pk_f16(p0, p1), pk_f16(p2, p3), 0, 1, 2, 3);
        lacc[u] = __builtin_amdgcn_mfma_f32_16x16x16f16(pa[u][j], vone, lacc[u], 0, 0, 0);
      }
    }

    // PV: O[t][c] += P[t][s] V^T[s][c]; vb shared across u.
    // conflict-free: slot8 = (4j+quad)^l4 covers all 32 banks per quad-phase
    #pragma unroll
    for (int ct = 0; ct < 4; ct++) {
      const int c = ct * 16 + l4;
      #pragma unroll
      for (int j = 0; j < 4; j++) {
        const f16x4 vb = *reinterpret_cast<const f16x4*>(
            vsc + c * 64 + (((4 * j + quad) ^ l4) << 2));
        #pragma unroll
        for (int u = 0; u < 2; u++) {
          oacc[u][ct] = __builtin_amdgcn_mfma_f32_16x16x16f16(pa[u][j], vb, oacc[u][ct], 0, 0, 0);
        }
      }
    }
    __syncthreads();   // drains prefetch; buf[cur] reads done before overwrite
  }

  // epilogue: O / l (both already in C layout), write a^T (B, L, C)
  const int bi = hb >> 4, h = hb & 15;
  #pragma unroll
  for (int u = 0; u < 2; u++) {
    float linv[4];
    #pragma unroll
    for (int r = 0; r < 4; r++) { linv[r] = 1.f / lacc[u][r]; }
    #pragma unroll
    for (int ct = 0; ct < 4; ct++) {
      #pragma unroll
      for (int r = 0; r < 4; r++) {
        const int t = t0 + wave * 32 + u * 16 + quad * 4 + r;
        const int c = h * CH_ + ct * 16 + l4;
        aT[(size_t)(bi * L_ + t) * C_ + c] = (bf16)(oacc[u][ct][r] * linv[r]);
      }
    }
  }
}

// ---------------------------------------------------------------------------
// Proj GEMM + bias + residual: out = x_norm + proj_w @ a + proj_b  (fp32 out)
// ---------------------------------------------------------------------------
__global__ __launch_bounds__(256, 4) void proj_gemm_kernel(const bf16* __restrict__ Wp,
                                                           const bf16* __restrict__ aT,
                                                           const float* __restrict__ bias,
                                                           const bf16* __restrict__ xnb,
                                                           float* __restrict__ out) {
  __shared__ bf16 As[2 * 128 * 32], Bs[2 * 128 * 32];
  const int bi = blockIdx.z;
  const int m0 = blockIdx.y * 128, n0 = blockIdx.x * 128;

  f32x4 acc[4][4];
  #pragma unroll
  for (int i = 0; i < 4; i++) {
    #pragma unroll
    for (int j = 0; j < 4; j++) { acc[i][j] = (f32x4){0.f, 0.f, 0.f, 0.f}; }
  }

  gemm128_bt(Wp, aT + (size_t)bi * L_ * C_, C_, C_, C_, m0, n0, As, Bs, acc);

  const int tid = threadIdx.x;
  const int wave = tid >> 6, lane = tid & 63;
  const int wm = (wave >> 1) * 64, wn = (wave & 1) * 64;
  const int l4 = lane & 15, quad = lane >> 4;

  #pragma unroll
  for (int i = 0; i < 4; i++) {
    const int ob = m0 + wm + i * 16 + quad * 4;
    float bb[4];
    #pragma unroll
    for (int rg = 0; rg < 4; rg++) { bb[rg] = bias[ob + rg]; }
    #pragma unroll
    for (int j = 0; j < 4; j++) {
      const int l = n0 + wn + j * 16 + l4;
      #pragma unroll
      for (int rg = 0; rg < 4; rg++) {
        const size_t idx = (size_t)(bi * C_ + ob + rg) * L_ + l;
        out[idx] = acc[i][j][rg] + bb[rg] + (float)xnb[idx];
      }
    }
  }
}

// ---------------------------------------------------------------------------
extern "C" void kernel_launch(void* const* d_in, const int* in_sizes, int n_in,
                              void* d_out, int out_size, void* d_ws, size_t ws_size,
                              hipStream_t stream) {
  (void)in_sizes; (void)n_in; (void)out_size; (void)ws_size;
  const float* x      = (const float*)d_in[0];
  const float* norm_w = (const float*)d_in[1];
  const float* norm_b = (const float*)d_in[2];
  const float* qkv_w  = (const float*)d_in[3];
  const float* qkv_b  = (const float*)d_in[4];
  const float* proj_w = (const float*)d_in[5];
  const float* proj_b = (const float*)d_in[6];
  float* out = (float*)d_out;

  char* w = (char*)d_ws;
  auto alloc = [&](size_t bytes) {
    char* p = w;
    w += (bytes + 255) & ~(size_t)255;
    return p;
  };
  bf16*  xnb   = (bf16*)alloc((size_t)B_ * C_ * L_ * 2);       // x_norm (B,C,L)
  bf16*  xT    = (bf16*)alloc((size_t)B_ * L_ * C_ * 2);       // x_norm^T (B,L,C)
  bf16*  wq    = (bf16*)alloc((size_t)3 * C_ * C_ * 2);        // qkv_w bf16
  bf16*  wp    = (bf16*)alloc((size_t)C_ * C_ * 2);            // proj_w bf16
  bf16*  qT    = (bf16*)alloc((size_t)B_ * H_ * L_ * CH_ * 2); // q (b,h,L,64), pre-scaled
  bf16*  kT    = (bf16*)alloc((size_t)B_ * H_ * L_ * CH_ * 2); // k (b,h,L,64)
  f16*   vB    = (f16*)alloc((size_t)B_ * H_ * CH_ * L_ * 2);  // v (b,h,64,L) f16, swizzled
  bf16*  aTb   = (bf16*)alloc((size_t)B_ * L_ * C_ * 2);       // a^T (B,L,C)
  float* stats = (float*)alloc((size_t)B_ * NG_ * 2 * 4);      // per-(b,g) sum/sumsq

  (void)hipMemsetAsync(stats, 0, (size_t)B_ * NG_ * 2 * 4, stream);
  cvt_bf16_kernel<<<(3 * C_ * C_ / 4) / 256, 256, 0, stream>>>(qkv_w, wq, 3 * C_ * C_ / 4);
  cvt_bf16_kernel<<<(C_ * C_ / 4) / 256, 256, 0, stream>>>(proj_w, wp, C_ * C_ / 4);
  gn_stats_kernel<<<B_ * NG_ * 8, 256, 0, stream>>>(x, stats);
  gn_apply_kernel<<<B_ * NG_ * 4, 256, 0, stream>>>(x, norm_w, norm_b, stats, xnb, xT);
  qkv_gemm_kernel<<<dim3(L_ / 128, 3 * C_ / 128, B_), 256, 0, stream>>>(wq, xT, qkv_b, qT, kT, vB);
  attn_kernel<<<1024, 256, 0, stream>>>(qT, kT, vB, aTb);
  proj_gemm_kernel<<<dim3(L_ / 128, C_ / 128, B_), 256, 0, stream>>>(wp, aTb, proj_b, xnb, out);
}

// Round 9
// 261.871 us; speedup vs baseline: 1.0657x; 1.0657x over previous
//
#include <hip/hip_runtime.h>
#include <cstdint>
#include <cstddef>

#define B_   8
#define C_   1024
#define L_   1024
#define H_   16
#define CH_  64     // head dim = C/H
#define NG_  32     // groups
#define CPG_ 32     // channels per group

typedef __bf16 bf16;
typedef _Float16 f16;
typedef bf16  bf16x8 __attribute__((ext_vector_type(8)));
typedef bf16  bf16x4 __attribute__((ext_vector_type(4)));
typedef f16   f16x4  __attribute__((ext_vector_type(4)));
typedef f16   f16x2  __attribute__((ext_vector_type(2)));
typedef float f32x4  __attribute__((ext_vector_type(4)));

// log2(e)/8 : folds the attention scale (1/8) AND the exp->exp2 conversion into q
#define QSCALE 0.1803368801111203f

// ---------------------------------------------------------------------------
// async global->LDS, 16B per lane. LDS dest = wave-uniform base + lane*16.
// ---------------------------------------------------------------------------
__device__ __forceinline__ void async_cp16(void* lds, const void* g) {
  __builtin_amdgcn_global_load_lds((__attribute__((address_space(1))) void*)g,
                                   (__attribute__((address_space(3))) void*)lds,
                                   16, 0, 0);
}

// packed f32->f16 rtz convert, bit-cast to our f16x2
__device__ __forceinline__ f16x2 pk_f16(float a, float b) {
  return __builtin_bit_cast(f16x2, __builtin_amdgcn_cvt_pkrtz(a, b));
}

// LDS element offset, 64-elem (128B) rows, 8 chunks of 8 elems, XOR swizzle
// (row&7): ds_read_b128 of 16 rows at fixed logical chunk -> 2-way (free).
__device__ __forceinline__ int sw64(int r, int c) {
  return r * 64 + ((c ^ (r & 7)) << 3);
}

// ---------------------------------------------------------------------------
// Fused prep: weight fp32->bf16 casts + GroupNorm partial stats, one dispatch.
// blocks [0,2048): gn_stats (8 per (b,g), f32 atomics into stats[])
// blocks [2048,5120): cvt qkv_w (3*C*C elems)
// blocks [5120,6144): cvt proj_w (C*C elems)
// ---------------------------------------------------------------------------
__global__ __launch_bounds__(256) void prep_kernel(const float* __restrict__ x,
                                                   const float* __restrict__ qkv_w,
                                                   const float* __restrict__ proj_w,
                                                   float* __restrict__ stats,
                                                   bf16* __restrict__ wq,
                                                   bf16* __restrict__ wp) {
  const int tid = threadIdx.x;
  if (blockIdx.x < 2048) {
    const int bg = blockIdx.x >> 3, sl = blockIdx.x & 7;
    const float* xs = x + (size_t)bg * CPG_ * L_;
    const int c = tid >> 3;
    const int lbase = sl * 128 + (tid & 7) * 4;

    float s = 0.f, s2 = 0.f;
    #pragma unroll
    for (int t = 0; t < 4; t++) {
      float4 f = *reinterpret_cast<const float4*>(xs + (size_t)c * L_ + lbase + t * 32);
      s  += f.x + f.y + f.z + f.w;
      s2 += f.x * f.x + f.y * f.y + f.z * f.z + f.w * f.w;
    }
    __shared__ float rs[256], rs2[256];
    rs[tid] = s; rs2[tid] = s2;
    __syncthreads();
    for (int d = 128; d > 0; d >>= 1) {
      if (tid < d) { rs[tid] += rs[tid + d]; rs2[tid] += rs2[tid + d]; }
      __syncthreads();
    }
    if (tid == 0) {
      atomicAdd(&stats[bg * 2],     rs[0]);
      atomicAdd(&stats[bg * 2 + 1], rs2[0]);
    }
  } else {
    const float* src;
    bf16* dst;
    int i;
    if (blockIdx.x < 5120) {
      src = qkv_w; dst = wq; i = (blockIdx.x - 2048) * 256 + tid;
    } else {
      src = proj_w; dst = wp; i = (blockIdx.x - 5120) * 256 + tid;
    }
    float4 f = reinterpret_cast<const float4*>(src)[i];
    bf16x4 o;
    o[0] = (bf16)f.x; o[1] = (bf16)f.y; o[2] = (bf16)f.z; o[3] = (bf16)f.w;
    reinterpret_cast<bf16x4*>(dst)[i] = o;
  }
}

// ---------------------------------------------------------------------------
// GroupNorm apply: 4 blocks per (b,g), each covers 256 l. Writes x_norm bf16
// (B,C,L) for residual and x_norm^T bf16 (B,L,C) via LDS transpose.
// ---------------------------------------------------------------------------
__global__ __launch_bounds__(256) void gn_apply_kernel(const float* __restrict__ x,
                                                       const float* __restrict__ gw,
                                                       const float* __restrict__ gb,
                                                       const float* __restrict__ stats,
                                                       bf16* __restrict__ xnb,
                                                       bf16* __restrict__ xT) {
  const int bg = blockIdx.x >> 2, l0 = (blockIdx.x & 3) * 256;
  const int b = bg >> 5, g = bg & 31;
  const int tid = threadIdx.x;
  const float* xs = x + (size_t)bg * CPG_ * L_;

  const float mean = stats[bg * 2] * (1.f / 32768.f);
  const float var  = stats[bg * 2 + 1] * (1.f / 32768.f) - mean * mean;
  const float inv  = rsqrtf(var + 1e-5f);

  __shared__ float tile[CPG_][257];
  #pragma unroll 4
  for (int c = 0; c < CPG_; c++) {
    const int gc = g * CPG_ + c;
    const float y = (xs[(size_t)c * L_ + l0 + tid] - mean) * inv * gw[gc] + gb[gc];
    xnb[(size_t)(b * C_ + gc) * L_ + l0 + tid] = (bf16)y;
    tile[c][tid] = y;
  }
  __syncthreads();
  const int c2 = tid & 31, lw = tid >> 5;
  #pragma unroll 4
  for (int jj = 0; jj < 32; jj++) {
    const int l = l0 + jj * 8 + lw;
    xT[(size_t)(b * L_ + l) * C_ + g * CPG_ + c2] = (bf16)tile[c2][jj * 8 + lw];
  }
}

// ---------------------------------------------------------------------------
// GEMM mainloop: C[m][n] = sum_k A[m][k] * Bt[n][k].
// 128x128 block tile, BK=64, 4 waves in 2x2, each wave 64x64 (4x4 MFMA tiles).
// global_load_lds(16B) staging, sw64 XOR-swizzled LDS (128x64 per operand).
// (R7-proven structure; R8's BK=32 dbuf regressed — barrier vmcnt(0) drain
//  leaves only ~77cyc of compute to hide ~200-900cyc load latency.)
// ---------------------------------------------------------------------------
__device__ __forceinline__ void gemm128_bt(const bf16* __restrict__ A,
                                           const bf16* __restrict__ Bt,
                                           int lda, int ldb, int K,
                                           int m0, int n0,
                                           bf16* As, bf16* Bs,
                                           f32x4 acc[4][4]) {
  const int tid  = threadIdx.x;
  const int wave = tid >> 6, lane = tid & 63;
  const int wm = (wave >> 1) * 64, wn = (wave & 1) * 64;
  const int l4 = lane & 15, quad = lane >> 4;
  const int rsub = lane >> 3;                        // staging row within 8
  const int csrc = (((lane & 7) ^ rsub) << 3);       // swizzled src chunk

  const bf16* ga = A  + (size_t)(m0 + rsub) * lda + csrc;
  const bf16* gb = Bt + (size_t)(n0 + rsub) * ldb + csrc;

  for (int k0 = 0; k0 < K; k0 += 64) {
    __syncthreads();
    #pragma unroll
    for (int i = wave; i < 16; i += 4) {
      async_cp16(As + i * 512, ga + (size_t)(i * 8) * lda + k0);
      async_cp16(Bs + i * 512, gb + (size_t)(i * 8) * ldb + k0);
    }
    __syncthreads();

    #pragma unroll
    for (int kk = 0; kk < 2; kk++) {
      bf16x8 af[4], bfv[4];
      #pragma unroll
      for (int i = 0; i < 4; i++) {
        af[i] = *reinterpret_cast<const bf16x8*>(As + sw64(wm + i * 16 + l4, kk * 4 + quad));
      }
      #pragma unroll
      for (int j = 0; j < 4; j++) {
        bfv[j] = *reinterpret_cast<const bf16x8*>(Bs + sw64(wn + j * 16 + l4, kk * 4 + quad));
      }
      #pragma unroll
      for (int i = 0; i < 4; i++) {
        #pragma unroll
        for (int j = 0; j < 4; j++) {
          acc[i][j] = __builtin_amdgcn_mfma_f32_16x16x32_bf16(af[i], bfv[j], acc[i][j], 0, 0, 0);
        }
      }
    }
  }
}

// ---------------------------------------------------------------------------
// QKV GEMM: A = qkv_w bf16 (3072x1024), Bt = x_norm^T (per batch, 1024x1024).
// Epilogue: +bias; q scaled by log2(e)/8 -> (b,h,L,64); k -> (b,h,L,64);
// v -> fp16 (b,h,64,L) with an 8B-slot swizzle inside each 128B segment:
//   slot8' = slot8 ^ (c & 15)   (c = head channel)
// so that attention's LDS image gives conflict-free PV ds_read_b64.
// ---------------------------------------------------------------------------
__global__ __launch_bounds__(256) void qkv_gemm_kernel(const bf16* __restrict__ Wq,
                                                       const bf16* __restrict__ xT,
                                                       const float* __restrict__ bias,
                                                       bf16* __restrict__ qT,
                                                       bf16* __restrict__ kT,
                                                       f16* __restrict__ vB) {
  __shared__ bf16 As[128 * 64], Bs[128 * 64];
  const int bi = blockIdx.z;
  const int m0 = blockIdx.y * 128, n0 = blockIdx.x * 128;

  f32x4 acc[4][4];
  #pragma unroll
  for (int i = 0; i < 4; i++) {
    #pragma unroll
    for (int j = 0; j < 4; j++) { acc[i][j] = (f32x4){0.f, 0.f, 0.f, 0.f}; }
  }

  gemm128_bt(Wq, xT + (size_t)bi * L_ * C_, C_, C_, C_, m0, n0, As, Bs, acc);

  const int tid = threadIdx.x;
  const int wave = tid >> 6, lane = tid & 63;
  const int wm = (wave >> 1) * 64, wn = (wave & 1) * 64;
  const int l4 = lane & 15, quad = lane >> 4;

  #pragma unroll
  for (int i = 0; i < 4; i++) {
    const int ob = m0 + wm + i * 16 + quad * 4;   // rows ob..ob+3 (same head/section)
    const int h = ob / 192, r = ob % 192;
    const int sec = r >> 6, c = r & 63;
    float bb[4];
    #pragma unroll
    for (int rg = 0; rg < 4; rg++) { bb[rg] = bias[ob + rg]; }
    #pragma unroll
    for (int j = 0; j < 4; j++) {
      const int l = n0 + wn + j * 16 + l4;
      f32x4 a = acc[i][j];
      if (sec == 2) {
        const int e = l & 63, g64 = l >> 6;
        #pragma unroll
        for (int rg = 0; rg < 4; rg++) {
          const int cc = c + rg;
          const int ep = ((((e >> 2) ^ cc) & 15) << 2) | (e & 3);
          vB[(size_t)((bi * H_ + h) * CH_ + cc) * L_ + (g64 << 6) + ep] =
              (f16)(a[rg] + bb[rg]);
        }
      } else {
        const float sc = (sec == 0) ? QSCALE : 1.0f;
        bf16* dst = (sec == 0 ? qT : kT) + (size_t)((bi * H_ + h) * L_ + l) * CH_ + c;
        bf16x4 o;
        #pragma unroll
        for (int rg = 0; rg < 4; rg++) { o[rg] = (bf16)((a[rg] + bb[rg]) * sc); }
        *reinterpret_cast<bf16x4*>(dst) = o;
      }
    }
  }
}

// ---------------------------------------------------------------------------
// Flash attention, S^T formulation, 128 t-rows/block, grid 1024 (4 blocks/CU).
// LDS overlay (32KB total): Q tile (16KB) is consumed into registers right
// after staging, then its region is reused as K/V double-buffer slot 1.
// Double-buffered K/V prefetch overlaps compute; ONE barrier per s-iter.
// l (sum of exp) accumulated via MFMA with a ones-B operand.
// qT/kT: (head, L, 64) bf16 (q pre-scaled by log2(e)/8);
// vB: (head, 64, L) f16, 8B-slot-swizzled -> conflict-free PV ds_read_b64.
// out aT: (B, L, C) bf16.
// ---------------------------------------------------------------------------
__global__ __launch_bounds__(256, 4) void attn_kernel(const bf16* __restrict__ qT,
                                                      const bf16* __restrict__ kT,
                                                      const f16* __restrict__ vB,
                                                      bf16* __restrict__ aT) {
  const int tid = threadIdx.x, wave = tid >> 6, lane = tid & 63;
  const int l4 = lane & 15, quad = lane >> 4;
  const int rsub = lane >> 3;
  const int csrc = ((lane & 7) ^ rsub) << 3;   // swizzled source chunk (q/k only)

  // layout: buf0 K at 0, buf0 V at 8K; buf1 K at 16K, buf1 V at 24K.
  // Q initially staged at 16K (buf1 region), consumed to regs before buf1 use.
  __shared__ char smem[32768];

  const int tile = blockIdx.x;               // 0..1023
  const int t0 = (tile & 7) * 128;
  const int hb = tile >> 3;                  // b*16 + h
  const bf16* q = qT + (size_t)hb * L_ * CH_;
  const bf16* k = kT + (size_t)hb * L_ * CH_;
  const f16*  v = vB + (size_t)hb * CH_ * L_;

  // stage Q tile (16KB, at smem+16K) + first K/V tiles into buf 0
  {
    const bf16* gq = q + (size_t)t0 * CH_;
    #pragma unroll
    for (int i = wave; i < 16; i += 4) {
      async_cp16(smem + 16384 + i * 1024, gq + (i * 8 + rsub) * 64 + csrc);
    }
    #pragma unroll
    for (int i = wave; i < 8; i += 4) {
      async_cp16(smem + i * 1024, k + (size_t)(i * 8 + rsub) * 64 + csrc);
      async_cp16(smem + 8192 + i * 1024, v + (size_t)(i * 8 + rsub) * L_ + ((lane & 7) << 3));
    }
  }
  __syncthreads();

  // Q as B-operand: B[k=c=quad*8+jj][n=t=l4]; two 16-col groups per wave (u)
  bf16x8 bq0[2], bq1[2];
  {
    const bf16* qs = (const bf16*)(smem + 16384);
    #pragma unroll
    for (int u = 0; u < 2; u++) {
      bq0[u] = *reinterpret_cast<const bf16x8*>(qs + sw64(wave * 32 + u * 16 + l4, quad));
      bq1[u] = *reinterpret_cast<const bf16x8*>(qs + sw64(wave * 32 + u * 16 + l4, quad + 4));
    }
  }
  __syncthreads();   // all waves have Q in regs; qs region is now free (buf1)

  f32x4 oacc[2][4];              // [u][ct], rows t=quad*4+r, cols c=ct*16+l4
  f32x4 lacc[2];                 // running sum(exp), same row layout as oacc
  float m_s[2];                  // running max for t = u*16 + l4
  #pragma unroll
  for (int u = 0; u < 2; u++) {
    #pragma unroll
    for (int ct = 0; ct < 4; ct++) { oacc[u][ct] = (f32x4){0.f, 0.f, 0.f, 0.f}; }
    lacc[u] = (f32x4){0.f, 0.f, 0.f, 0.f};
    m_s[u] = -1e30f;
  }

  const f16x4 vone = {(f16)1.f, (f16)1.f, (f16)1.f, (f16)1.f};

  for (int it = 0; it < 16; it++) {
    const int cur = it & 1;
    // prefetch next K/V tile into the other buffer; overlaps compute below
    if (it < 15) {
      const int s1 = (it + 1) * 64;
      char* nb = smem + (cur ^ 1) * 16384;
      const bf16* gk = k + (size_t)s1 * CH_;
      const f16*  gv = v + s1;
      #pragma unroll
      for (int i = wave; i < 8; i += 4) {
        async_cp16(nb + i * 1024, gk + (size_t)(i * 8 + rsub) * 64 + csrc);
        async_cp16(nb + 8192 + i * 1024, gv + (size_t)(i * 8 + rsub) * L_ + ((lane & 7) << 3));
      }
    }
    const bf16* ksc = (const bf16*)(smem + cur * 16384);
    const f16*  vsc = (const f16*)(smem + cur * 16384 + 8192);

    // S^T tiles: lane holds S[s=16j+quad*4+r][t = u*16 + l4] in st[u][j][r]
    f32x4 st[2][4];
    #pragma unroll
    for (int j = 0; j < 4; j++) {
      const bf16x8 ak0 = *reinterpret_cast<const bf16x8*>(ksc + sw64(j * 16 + l4, quad));
      const bf16x8 ak1 = *reinterpret_cast<const bf16x8*>(ksc + sw64(j * 16 + l4, quad + 4));
      #pragma unroll
      for (int u = 0; u < 2; u++) {
        f32x4 z = (f32x4){0.f, 0.f, 0.f, 0.f};
        z = __builtin_amdgcn_mfma_f32_16x16x32_bf16(ak0, bq0[u], z, 0, 0, 0);
        z = __builtin_amdgcn_mfma_f32_16x16x32_bf16(ak1, bq1[u], z, 0, 0, 0);
        st[u][j] = z;
      }
    }

    // running-max update (base-2 domain; q pre-scaled by log2(e)/8)
    float alpha[2], mn[2];
    #pragma unroll
    for (int u = 0; u < 2; u++) {
      float mx = fmaxf(fmaxf(st[u][0][0], st[u][0][1]), fmaxf(st[u][0][2], st[u][0][3]));
      #pragma unroll
      for (int j = 1; j < 4; j++) {
        mx = fmaxf(mx, fmaxf(fmaxf(st[u][j][0], st[u][j][1]), fmaxf(st[u][j][2], st[u][j][3])));
      }
      mx = fmaxf(mx, __shfl_xor(mx, 16));
      mx = fmaxf(mx, __shfl_xor(mx, 32));
      mn[u] = fmaxf(m_s[u], mx);
      alpha[u] = __builtin_amdgcn_exp2f(m_s[u] - mn[u]);
      m_s[u] = mn[u];
    }

    // rescale history only when some row's max moved (alpha != 1 exactly)
    if (__any(alpha[0] != 1.0f || alpha[1] != 1.0f)) {
      #pragma unroll
      for (int u = 0; u < 2; u++) {
        float ar[4];
        #pragma unroll
        for (int r = 0; r < 4; r++) { ar[r] = __shfl(alpha[u], quad * 4 + r); }
        #pragma unroll
        for (int ct = 0; ct < 4; ct++) {
          #pragma unroll
          for (int r = 0; r < 4; r++) { oacc[u][ct][r] *= ar[r]; }
        }
        #pragma unroll
        for (int r = 0; r < 4; r++) { lacc[u][r] *= ar[r]; }
      }
    }

    // P = exp2(S - m) as f16 A-fragments; l accumulated via MFMA with ones-B
    f16x4 pa[2][4];
    #pragma unroll
    for (int u = 0; u < 2; u++) {
      #pragma unroll
      for (int j = 0; j < 4; j++) {
        const float p0 = __builtin_amdgcn_exp2f(st[u][j][0] - mn[u]);
        const float p1 = __builtin_amdgcn_exp2f(st[u][j][1] - mn[u]);
        const float p2 = __builtin_amdgcn_exp2f(st[u][j][2] - mn[u]);
        const float p3 = __builtin_amdgcn_exp2f(st[u][j][3] - mn[u]);
        pa[u][j] = __builtin_shufflevector(pk_f16(p0, p1), pk_f16(p2, p3), 0, 1, 2, 3);
        lacc[u] = __builtin_amdgcn_mfma_f32_16x16x16f16(pa[u][j], vone, lacc[u], 0, 0, 0);
      }
    }

    // PV: O[t][c] += P[t][s] V^T[s][c]; vb shared across u.
    // conflict-free: slot8 = (4j+quad)^l4 covers all 32 banks per quad-phase
    #pragma unroll
    for (int ct = 0; ct < 4; ct++) {
      const int c = ct * 16 + l4;
      #pragma unroll
      for (int j = 0; j < 4; j++) {
        const f16x4 vb = *reinterpret_cast<const f16x4*>(
            vsc + c * 64 + (((4 * j + quad) ^ l4) << 2));
        #pragma unroll
        for (int u = 0; u < 2; u++) {
          oacc[u][ct] = __builtin_amdgcn_mfma_f32_16x16x16f16(pa[u][j], vb, oacc[u][ct], 0, 0, 0);
        }
      }
    }
    __syncthreads();   // drains prefetch; buf[cur] reads done before overwrite
  }

  // epilogue: O / l (both already in C layout), write a^T (B, L, C)
  const int bi = hb >> 4, h = hb & 15;
  #pragma unroll
  for (int u = 0; u < 2; u++) {
    float linv[4];
    #pragma unroll
    for (int r = 0; r < 4; r++) { linv[r] = 1.f / lacc[u][r]; }
    #pragma unroll
    for (int ct = 0; ct < 4; ct++) {
      #pragma unroll
      for (int r = 0; r < 4; r++) {
        const int t = t0 + wave * 32 + u * 16 + quad * 4 + r;
        const int c = h * CH_ + ct * 16 + l4;
        aT[(size_t)(bi * L_ + t) * C_ + c] = (bf16)(oacc[u][ct][r] * linv[r]);
      }
    }
  }
}

// ---------------------------------------------------------------------------
// Proj GEMM + bias + residual: out = x_norm + proj_w @ a + proj_b  (fp32 out)
// ---------------------------------------------------------------------------
__global__ __launch_bounds__(256) void proj_gemm_kernel(const bf16* __restrict__ Wp,
                                                        const bf16* __restrict__ aT,
                                                        const float* __restrict__ bias,
                                                        const bf16* __restrict__ xnb,
                                                        float* __restrict__ out) {
  __shared__ bf16 As[128 * 64], Bs[128 * 64];
  const int bi = blockIdx.z;
  const int m0 = blockIdx.y * 128, n0 = blockIdx.x * 128;

  f32x4 acc[4][4];
  #pragma unroll
  for (int i = 0; i < 4; i++) {
    #pragma unroll
    for (int j = 0; j < 4; j++) { acc[i][j] = (f32x4){0.f, 0.f, 0.f, 0.f}; }
  }

  gemm128_bt(Wp, aT + (size_t)bi * L_ * C_, C_, C_, C_, m0, n0, As, Bs, acc);

  const int tid = threadIdx.x;
  const int wave = tid >> 6, lane = tid & 63;
  const int wm = (wave >> 1) * 64, wn = (wave & 1) * 64;
  const int l4 = lane & 15, quad = lane >> 4;

  #pragma unroll
  for (int i = 0; i < 4; i++) {
    const int ob = m0 + wm + i * 16 + quad * 4;
    float bb[4];
    #pragma unroll
    for (int rg = 0; rg < 4; rg++) { bb[rg] = bias[ob + rg]; }
    #pragma unroll
    for (int j = 0; j < 4; j++) {
      const int l = n0 + wn + j * 16 + l4;
      #pragma unroll
      for (int rg = 0; rg < 4; rg++) {
        const size_t idx = (size_t)(bi * C_ + ob + rg) * L_ + l;
        out[idx] = acc[i][j][rg] + bb[rg] + (float)xnb[idx];
      }
    }
  }
}

// ---------------------------------------------------------------------------
extern "C" void kernel_launch(void* const* d_in, const int* in_sizes, int n_in,
                              void* d_out, int out_size, void* d_ws, size_t ws_size,
                              hipStream_t stream) {
  (void)in_sizes; (void)n_in; (void)out_size; (void)ws_size;
  const float* x      = (const float*)d_in[0];
  const float* norm_w = (const float*)d_in[1];
  const float* norm_b = (const float*)d_in[2];
  const float* qkv_w  = (const float*)d_in[3];
  const float* qkv_b  = (const float*)d_in[4];
  const float* proj_w = (const float*)d_in[5];
  const float* proj_b = (const float*)d_in[6];
  float* out = (float*)d_out;

  char* w = (char*)d_ws;
  auto alloc = [&](size_t bytes) {
    char* p = w;
    w += (bytes + 255) & ~(size_t)255;
    return p;
  };
  bf16*  xnb   = (bf16*)alloc((size_t)B_ * C_ * L_ * 2);       // x_norm (B,C,L)
  bf16*  xT    = (bf16*)alloc((size_t)B_ * L_ * C_ * 2);       // x_norm^T (B,L,C)
  bf16*  wq    = (bf16*)alloc((size_t)3 * C_ * C_ * 2);        // qkv_w bf16
  bf16*  wp    = (bf16*)alloc((size_t)C_ * C_ * 2);            // proj_w bf16
  bf16*  qT    = (bf16*)alloc((size_t)B_ * H_ * L_ * CH_ * 2); // q (b,h,L,64), pre-scaled
  bf16*  kT    = (bf16*)alloc((size_t)B_ * H_ * L_ * CH_ * 2); // k (b,h,L,64)
  f16*   vB    = (f16*)alloc((size_t)B_ * H_ * CH_ * L_ * 2);  // v (b,h,64,L) f16, swizzled
  bf16*  aTb   = (bf16*)alloc((size_t)B_ * L_ * C_ * 2);       // a^T (B,L,C)
  float* stats = (float*)alloc((size_t)B_ * NG_ * 2 * 4);      // per-(b,g) sum/sumsq

  (void)hipMemsetAsync(stats, 0, (size_t)B_ * NG_ * 2 * 4, stream);
  prep_kernel<<<6144, 256, 0, stream>>>(x, qkv_w, proj_w, stats, wq, wp);
  gn_apply_kernel<<<B_ * NG_ * 4, 256, 0, stream>>>(x, norm_w, norm_b, stats, xnb, xT);
  qkv_gemm_kernel<<<dim3(L_ / 128, 3 * C_ / 128, B_), 256, 0, stream>>>(wq, xT, qkv_b, qT, kT, vB);
  attn_kernel<<<1024, 256, 0, stream>>>(qT, kT, vB, aTb);
  proj_gemm_kernel<<<dim3(L_ / 128, C_ / 128, B_), 256, 0, stream>>>(wp, aTb, proj_b, xnb, out);
}